// Round 7
// baseline (1106.923 us; speedup 1.0000x reference)
//
#include <hip/hip_runtime.h>
#include <hip/hip_cooperative_groups.h>
#include <math.h>

namespace cg = cooperative_groups;

#define LRELU(v) ((v) > 0.f ? (v) : 0.2f * (v))

struct Params {
    const float *x, *W1, *b1, *W2, *b2, *gamma, *beta, *W3, *b3;
    const float *Wv, *bv, *Wo, *bo, *T2, *Ws, *bs;
    float *h2, *stats, *h4, *Mt, *opart, *out;
};

// ===========================================================================
// FUSED cooperative kernel: 1664 blocks x 256 threads, 4 phases + grid.sync.
// Phase work identical to the verified R6 kernels (absmax 0.0).
// ===========================================================================
__global__ __launch_bounds__(256, 7) void fused_all(Params p)
{
    cg::grid_group grid = cg::this_grid();
    __shared__ float s1[1280];   // P1: xs[256] | h1s[512] | ssum[256] | ssq[256]
    __shared__ float s2[640];    // P2: a[256] | h3s[128] | vss[128] | h4s[128]
    __shared__ float mi[2560];   // P3: [20 cols][128 i]
    const int t = threadIdx.x;
    const int b = blockIdx.x;

    // ---------------- P1: h1 -> h2 -> BN stats (blocks 0..511, 2 rows) -----
    if (b < 512) {
        float* xs = s1;            // [256]
        float* h1s = s1 + 256;     // [512]
        float* ssum = s1 + 768;    // [256]
        float* ssq = s1 + 1024;    // [256]
        const int r0 = b * 2;

        xs[t] = p.x[r0 * 128 + t];
        __syncthreads();
        {
            float a0 = p.b1[t], a1 = a0;
            for (int k = 0; k < 128; ++k) {
                float w = p.W1[k * 256 + t];
                a0 += xs[k] * w;
                a1 += xs[128 + k] * w;
            }
            h1s[t] = LRELU(a0);
            h1s[256 + t] = LRELU(a1);
        }
        __syncthreads();
        {
            const int c = t & 127;
            const int rr = t >> 7;
            float a = p.b2[c];
            for (int k = 0; k < 256; ++k)
                a += h1s[rr * 256 + k] * p.W2[k * 128 + c];
            p.h2[(r0 + rr) * 128 + c] = a;
            ssum[t] = a;
            ssq[t] = a * a;
        }
        __syncthreads();
        if (t < 128)      atomicAdd(p.stats + t, ssum[t] + ssum[128 + t]);
        else { int c = t - 128; atomicAdd(p.stats + 128 + c, ssq[c] + ssq[128 + c]); }
    }
    __threadfence();
    grid.sync();

    // ---------------- P2: BN -> h3 -> attn -> h4 -> Mt (blocks 0..511) -----
    if (b < 512) {
        float* a = s2;             // [256]
        float* h3s = s2 + 256;     // [128]
        float* vss = s2 + 384;     // [128]
        float* h4s = s2 + 512;     // [128]
        const int r0 = b * 2;
        {
            const int c = t & 127;
            float s = p.stats[c], ss = p.stats[128 + c];
            float mean = s * (1.f / 1024.f);
            float var = ss * (1.f / 1024.f) - mean * mean;
            float rstd = rsqrtf(var + 1e-5f);
            float v = (p.h2[r0 * 128 + t] - mean) * rstd * p.gamma[c] + p.beta[c];
            a[t] = LRELU(v);
        }
        __syncthreads();
        const int row = t >> 6, col = t & 63;
        if (t < 128) {
            float acc = p.b3[col];
            for (int k = 0; k < 128; ++k) acc += a[row * 128 + k] * p.W3[k * 64 + col];
            h3s[row * 64 + col] = LRELU(acc);
        }
        __syncthreads();
        if (t < 128) {
            float acc = p.bv[col];
            for (int k = 0; k < 64; ++k) acc += h3s[row * 64 + k] * p.Wv[k * 64 + col];
            vss[row * 64 + col] = acc;
        }
        __syncthreads();
        if (t < 128) {
            float acc = p.bo[col];
            for (int k = 0; k < 64; ++k) acc += vss[row * 64 + k] * p.Wo[k * 64 + col];
            float h4 = h3s[row * 64 + col] + acc;
            h4s[row * 64 + col] = h4;
            p.h4[(r0 + row) * 64 + col] = h4;
        }
        __syncthreads();
        if (t < 250) {
            float m0 = 0.f, m1 = 0.f;
            for (int k = 0; k < 64; ++k) {
                float w = p.T2[k * 250 + t];
                m0 += h4s[k] * w;
                m1 += h4s[64 + k] * w;
            }
            p.Mt[(size_t)t * 1024 + r0]     = m0;
            p.Mt[(size_t)t * 1024 + r0 + 1] = m1;
        } else {
            p.Mt[(size_t)t * 1024 + r0]     = 0.f;
            p.Mt[(size_t)t * 1024 + r0 + 1] = 0.f;
        }
        if (t < 4) {
            p.Mt[(size_t)(256 + t) * 1024 + r0]     = 0.f;
            p.Mt[(size_t)(256 + t) * 1024 + r0 + 1] = 0.f;
        }
    }
    __threadfence();
    grid.sync();

    // ---------------- P3: all-pairs L1+exp (all 1664 blocks) ---------------
    {
        const int jt = b / 104;
        const int rem = b - jt * 104;
        const int ct = rem >> 3;
        const int ic = rem & 7;
        const int jl = t & 63, cl = t >> 6;
        const int j = jt * 64 + jl;
        const int c = ct * 4 + cl;
        const int i0 = ic * 128;

        for (int qq = 0; qq < 10; ++qq) {
            int idx = qq * 256 + t;
            int cc = idx >> 7, il = idx & 127;
            mi[idx] = p.Mt[(size_t)(ct * 20 + cc) * 1024 + i0 + il];
        }
        float mj0 = p.Mt[(size_t)(c * 5 + 0) * 1024 + j];
        float mj1 = p.Mt[(size_t)(c * 5 + 1) * 1024 + j];
        float mj2 = p.Mt[(size_t)(c * 5 + 2) * 1024 + j];
        float mj3 = p.Mt[(size_t)(c * 5 + 3) * 1024 + j];
        float mj4 = p.Mt[(size_t)(c * 5 + 4) * 1024 + j];
        __syncthreads();

        const float2* m0 = (const float2*)(mi + (cl * 5 + 0) * 128);
        const float2* m1 = (const float2*)(mi + (cl * 5 + 1) * 128);
        const float2* m2 = (const float2*)(mi + (cl * 5 + 2) * 128);
        const float2* m3 = (const float2*)(mi + (cl * 5 + 3) * 128);
        const float2* m4 = (const float2*)(mi + (cl * 5 + 4) * 128);

        float acc0 = 0.f, acc1 = 0.f;
        for (int q = 0; q < 64; ++q) {
            float2 v0 = m0[q], v1 = m1[q], v2 = m2[q], v3 = m3[q], v4 = m4[q];
            float d0 = fabsf(v0.x - mj0) + fabsf(v1.x - mj1) + fabsf(v2.x - mj2)
                     + fabsf(v3.x - mj3) + fabsf(v4.x - mj4);
            float d1 = fabsf(v0.y - mj0) + fabsf(v1.y - mj1) + fabsf(v2.y - mj2)
                     + fabsf(v3.y - mj3) + fabsf(v4.y - mj4);
            acc0 += __expf(-d0);
            acc1 += __expf(-d1);
        }
        p.opart[(size_t)(ic * 1024 + j) * 52 + c] = acc0 + acc1;
    }
    __threadfence();
    grid.sync();

    // ---------------- P4: reduce + score (blocks 0..255, 4 rows/block) -----
    if (b < 256) {
        const int w = t >> 6, lane = t & 63;
        const int j = b * 4 + w;
        float contrib = p.h4[j * 64 + lane] * p.Ws[lane];
        if (lane < 50) {
            float s = 0.f;
            for (int ic = 0; ic < 8; ++ic)
                s += p.opart[(size_t)(ic * 1024 + j) * 52 + lane];
            contrib += (s - 1.0f) * p.Ws[64 + lane];
        }
        for (int off = 32; off > 0; off >>= 1)
            contrib += __shfl_down(contrib, off, 64);
        if (lane == 0) p.out[j] = contrib + p.bs[0];
    }
}

// ===========================================================================
// Fallback path: the verified R6 4-kernel pipeline (used only if the
// cooperative launch is rejected, e.g. by graph capture).
// ===========================================================================
__global__ __launch_bounds__(256) void k1_mlp12(
    const float* __restrict__ x,
    const float* __restrict__ W1, const float* __restrict__ b1,
    const float* __restrict__ W2, const float* __restrict__ b2,
    float* __restrict__ h2g, float* __restrict__ stats)
{
    __shared__ float xs[256];
    __shared__ float h1s[512];
    __shared__ float ssum[256];
    __shared__ float ssq[256];
    const int t = threadIdx.x;
    const int r0 = blockIdx.x * 2;

    xs[t] = x[r0 * 128 + t];
    __syncthreads();
    {
        float a0 = b1[t], a1 = a0;
        for (int k = 0; k < 128; ++k) {
            float w = W1[k * 256 + t];
            a0 += xs[k] * w;
            a1 += xs[128 + k] * w;
        }
        h1s[t] = LRELU(a0);
        h1s[256 + t] = LRELU(a1);
    }
    __syncthreads();
    {
        const int c = t & 127;
        const int rr = t >> 7;
        float a = b2[c];
        for (int k = 0; k < 256; ++k)
            a += h1s[rr * 256 + k] * W2[k * 128 + c];
        h2g[(r0 + rr) * 128 + c] = a;
        ssum[t] = a;
        ssq[t] = a * a;
    }
    __syncthreads();
    if (t < 128)      atomicAdd(stats + t, ssum[t] + ssum[128 + t]);
    else { int c = t - 128; atomicAdd(stats + 128 + c, ssq[c] + ssq[128 + c]); }
}

__global__ __launch_bounds__(256) void k2_bn_attn_m(
    const float* __restrict__ h2g, const float* __restrict__ stats,
    const float* __restrict__ gamma, const float* __restrict__ beta,
    const float* __restrict__ W3, const float* __restrict__ b3,
    const float* __restrict__ Wv, const float* __restrict__ bv,
    const float* __restrict__ Wo, const float* __restrict__ bo,
    const float* __restrict__ T2,
    float* __restrict__ h4g, float* __restrict__ Mt)
{
    __shared__ float a[256];
    __shared__ float h3s[128];
    __shared__ float vss[128];
    __shared__ float h4s[128];
    const int t = threadIdx.x;
    const int r0 = blockIdx.x * 2;
    {
        const int c = t & 127;
        float s = stats[c], ss = stats[128 + c];
        float mean = s * (1.f / 1024.f);
        float var = ss * (1.f / 1024.f) - mean * mean;
        float rstd = rsqrtf(var + 1e-5f);
        float v = (h2g[r0 * 128 + t] - mean) * rstd * gamma[c] + beta[c];
        a[t] = LRELU(v);
    }
    __syncthreads();
    const int row = t >> 6, col = t & 63;
    if (t < 128) {
        float acc = b3[col];
        for (int k = 0; k < 128; ++k) acc += a[row * 128 + k] * W3[k * 64 + col];
        h3s[row * 64 + col] = LRELU(acc);
    }
    __syncthreads();
    if (t < 128) {
        float acc = bv[col];
        for (int k = 0; k < 64; ++k) acc += h3s[row * 64 + k] * Wv[k * 64 + col];
        vss[row * 64 + col] = acc;
    }
    __syncthreads();
    if (t < 128) {
        float acc = bo[col];
        for (int k = 0; k < 64; ++k) acc += vss[row * 64 + k] * Wo[k * 64 + col];
        float h4 = h3s[row * 64 + col] + acc;
        h4s[row * 64 + col] = h4;
        h4g[(r0 + row) * 64 + col] = h4;
    }
    __syncthreads();
    if (t < 250) {
        float m0 = 0.f, m1 = 0.f;
        for (int k = 0; k < 64; ++k) {
            float w = T2[k * 250 + t];
            m0 += h4s[k] * w;
            m1 += h4s[64 + k] * w;
        }
        Mt[(size_t)t * 1024 + r0]     = m0;
        Mt[(size_t)t * 1024 + r0 + 1] = m1;
    } else {
        Mt[(size_t)t * 1024 + r0]     = 0.f;
        Mt[(size_t)t * 1024 + r0 + 1] = 0.f;
    }
    if (t < 4) {
        Mt[(size_t)(256 + t) * 1024 + r0]     = 0.f;
        Mt[(size_t)(256 + t) * 1024 + r0 + 1] = 0.f;
    }
}

__global__ __launch_bounds__(256) void k3_pairs(
    const float* __restrict__ Mt, float* __restrict__ opart)
{
    __shared__ float mi[2560];
    const int t = threadIdx.x;
    const int b = blockIdx.x;
    const int jt = b / 104;
    const int rem = b - jt * 104;
    const int ct = rem >> 3;
    const int ic = rem & 7;
    const int jl = t & 63, cl = t >> 6;
    const int j = jt * 64 + jl;
    const int c = ct * 4 + cl;
    const int i0 = ic * 128;

    for (int qq = 0; qq < 10; ++qq) {
        int idx = qq * 256 + t;
        int cc = idx >> 7, il = idx & 127;
        mi[idx] = Mt[(size_t)(ct * 20 + cc) * 1024 + i0 + il];
    }
    float mj0 = Mt[(size_t)(c * 5 + 0) * 1024 + j];
    float mj1 = Mt[(size_t)(c * 5 + 1) * 1024 + j];
    float mj2 = Mt[(size_t)(c * 5 + 2) * 1024 + j];
    float mj3 = Mt[(size_t)(c * 5 + 3) * 1024 + j];
    float mj4 = Mt[(size_t)(c * 5 + 4) * 1024 + j];
    __syncthreads();

    const float2* m0 = (const float2*)(mi + (cl * 5 + 0) * 128);
    const float2* m1 = (const float2*)(mi + (cl * 5 + 1) * 128);
    const float2* m2 = (const float2*)(mi + (cl * 5 + 2) * 128);
    const float2* m3 = (const float2*)(mi + (cl * 5 + 3) * 128);
    const float2* m4 = (const float2*)(mi + (cl * 5 + 4) * 128);

    float acc0 = 0.f, acc1 = 0.f;
    for (int q = 0; q < 64; ++q) {
        float2 v0 = m0[q], v1 = m1[q], v2 = m2[q], v3 = m3[q], v4 = m4[q];
        float d0 = fabsf(v0.x - mj0) + fabsf(v1.x - mj1) + fabsf(v2.x - mj2)
                 + fabsf(v3.x - mj3) + fabsf(v4.x - mj4);
        float d1 = fabsf(v0.y - mj0) + fabsf(v1.y - mj1) + fabsf(v2.y - mj2)
                 + fabsf(v3.y - mj3) + fabsf(v4.y - mj4);
        acc0 += __expf(-d0);
        acc1 += __expf(-d1);
    }
    opart[(size_t)(ic * 1024 + j) * 52 + c] = acc0 + acc1;
}

__global__ __launch_bounds__(64) void k4_score(
    const float* __restrict__ h4g, const float* __restrict__ opart,
    const float* __restrict__ Ws, const float* __restrict__ bs,
    float* __restrict__ out)
{
    const int j = blockIdx.x, t = threadIdx.x;
    float contrib = h4g[j * 64 + t] * Ws[t];
    if (t < 50) {
        float s = 0.f;
        for (int ic = 0; ic < 8; ++ic)
            s += opart[(size_t)(ic * 1024 + j) * 52 + t];
        contrib += (s - 1.0f) * Ws[64 + t];
    }
    for (int off = 32; off > 0; off >>= 1)
        contrib += __shfl_down(contrib, off, 64);
    if (t == 0) out[j] = contrib + bs[0];
}

// ---------------------------------------------------------------------------
// ws layout (float offsets): h2@0 (131072) | stats@131072 (256) |
// h4@131328 (65536) | Mt@196864 (266240) | opart@463104 (425984)
// ---------------------------------------------------------------------------
extern "C" void kernel_launch(void* const* d_in, const int* in_sizes, int n_in,
                              void* d_out, int out_size, void* d_ws, size_t ws_size,
                              hipStream_t stream)
{
    Params p;
    p.x     = (const float*)d_in[0];
    p.W1    = (const float*)d_in[1];
    p.b1    = (const float*)d_in[2];
    p.W2    = (const float*)d_in[3];
    p.b2    = (const float*)d_in[4];
    p.gamma = (const float*)d_in[5];
    p.beta  = (const float*)d_in[6];
    p.W3    = (const float*)d_in[7];
    p.b3    = (const float*)d_in[8];
    p.Wv    = (const float*)d_in[9];
    p.bv    = (const float*)d_in[10];
    p.Wo    = (const float*)d_in[11];
    p.bo    = (const float*)d_in[12];
    p.T2    = (const float*)d_in[13];
    p.Ws    = (const float*)d_in[14];
    p.bs    = (const float*)d_in[15];

    float* ws = (float*)d_ws;
    p.h2    = ws + 0;
    p.stats = ws + 131072;
    p.h4    = ws + 131328;
    p.Mt    = ws + 196864;
    p.opart = ws + 463104;
    p.out   = (float*)d_out;

    hipMemsetAsync(p.stats, 0, 256 * sizeof(float), stream);

    void* args[] = { &p };
    hipError_t err = hipLaunchCooperativeKernel((const void*)fused_all,
                                                dim3(1664), dim3(256),
                                                args, 0, stream);
    if (err != hipSuccess) {
        // Fallback: verified 4-kernel pipeline (same math, same buffers).
        hipLaunchKernelGGL(k1_mlp12, dim3(512), dim3(256), 0, stream,
                           p.x, p.W1, p.b1, p.W2, p.b2, p.h2, (float*)p.stats);
        hipLaunchKernelGGL(k2_bn_attn_m, dim3(512), dim3(256), 0, stream,
                           p.h2, p.stats, p.gamma, p.beta, p.W3, p.b3,
                           p.Wv, p.bv, p.Wo, p.bo, p.T2, p.h4, p.Mt);
        hipLaunchKernelGGL(k3_pairs, dim3(1664), dim3(256), 0, stream,
                           p.Mt, p.opart);
        hipLaunchKernelGGL(k4_score, dim3(1024), dim3(64), 0, stream,
                           p.h4, p.opart, p.Ws, p.bs, p.out);
    }
}

// Round 8
// 223.240 us; speedup vs baseline: 4.9584x; 4.9584x over previous
//
#include <hip/hip_runtime.h>
#include <math.h>

#define LRELU(v) ((v) > 0.f ? (v) : 0.2f * (v))

// ===========================================================================
// Kernel A: fused k1+k2. 512 blocks x 256 threads, 2 rows/block.
// P1: h1 -> h2 (kept in LDS) -> BN-stats atomics.
// Software barrier: counter over 512 blocks (all co-resident: 2 blocks/CU
// guaranteed by __launch_bounds__(256,2) + 7.7 KB LDS; grid == 2*256 CUs).
// P2: BN (stats via agent-scope atomic loads) -> h3 -> attn -> h4 -> Mt.
// NO cg::grid_sync (measured 330 us/sync on R7 -- banned).
// ===========================================================================
__global__ __launch_bounds__(256, 2) void kA(
    const float* __restrict__ x,
    const float* __restrict__ W1, const float* __restrict__ b1,
    const float* __restrict__ W2, const float* __restrict__ b2,
    const float* __restrict__ gamma, const float* __restrict__ beta,
    const float* __restrict__ W3, const float* __restrict__ b3,
    const float* __restrict__ Wv, const float* __restrict__ bv,
    const float* __restrict__ Wo, const float* __restrict__ bo,
    const float* __restrict__ T2,
    float* __restrict__ stats, unsigned int* __restrict__ cnt,
    float* __restrict__ h4g, float* __restrict__ Mt)
{
    __shared__ float xs[256];
    __shared__ float h1s[512];
    __shared__ float h2loc[256];   // own 2 rows of h2 (t = rr*128 + c)
    __shared__ float sq[256];
    __shared__ float a[256];
    __shared__ float h3s[128];
    __shared__ float vss[128];
    __shared__ float h4s[128];
    const int t = threadIdx.x;
    const int r0 = blockIdx.x * 2;

    // ---- P1: h1 = lrelu(x@W1+b1), h2 = h1@W2+b2 ----
    xs[t] = x[r0 * 128 + t];
    __syncthreads();
    {
        float a0 = b1[t], a1 = a0;
        for (int k = 0; k < 128; ++k) {
            float w = W1[k * 256 + t];          // coalesced, feeds both rows
            a0 += xs[k] * w;
            a1 += xs[128 + k] * w;
        }
        h1s[t] = LRELU(a0);
        h1s[256 + t] = LRELU(a1);
    }
    __syncthreads();
    {
        const int c = t & 127;
        const int rr = t >> 7;
        float v = b2[c];
        for (int k = 0; k < 256; ++k)
            v += h1s[rr * 256 + k] * W2[k * 128 + c];
        h2loc[t] = v;                           // stays in LDS for P2
        sq[t] = v * v;
    }
    __syncthreads();
    if (t < 128)      atomicAdd(stats + t, h2loc[t] + h2loc[128 + t]);
    else { int c = t - 128; atomicAdd(stats + 128 + c, sq[c] + sq[128 + c]); }

    // ---- software barrier over 512 blocks ----
    __syncthreads();                            // drains this block's atomics (vmcnt(0))
    if (t == 0) {
        __threadfence();                        // release
        atomicAdd(cnt, 1u);
        while (__hip_atomic_load(cnt, __ATOMIC_RELAXED, __HIP_MEMORY_SCOPE_AGENT) < 512u)
            __builtin_amdgcn_s_sleep(2);
    }
    __syncthreads();
    __threadfence();                            // acquire

    // ---- P2: BN (batch stats) + lrelu ----
    {
        const int c = t & 127;
        float s  = __hip_atomic_load(stats + c,       __ATOMIC_RELAXED, __HIP_MEMORY_SCOPE_AGENT);
        float ss = __hip_atomic_load(stats + 128 + c, __ATOMIC_RELAXED, __HIP_MEMORY_SCOPE_AGENT);
        float mean = s * (1.f / 1024.f);
        float var = ss * (1.f / 1024.f) - mean * mean;
        float rstd = rsqrtf(var + 1e-5f);
        float v = (h2loc[t] - mean) * rstd * gamma[c] + beta[c];
        a[t] = LRELU(v);
    }
    __syncthreads();
    const int row = t >> 6, col = t & 63;
    if (t < 128) {
        float acc = b3[col];
        for (int k = 0; k < 128; ++k) acc += a[row * 128 + k] * W3[k * 64 + col];
        h3s[row * 64 + col] = LRELU(acc);
    }
    __syncthreads();
    if (t < 128) {
        float acc = bv[col];
        for (int k = 0; k < 64; ++k) acc += h3s[row * 64 + k] * Wv[k * 64 + col];
        vss[row * 64 + col] = acc;
    }
    __syncthreads();
    if (t < 128) {
        float acc = bo[col];
        for (int k = 0; k < 64; ++k) acc += vss[row * 64 + k] * Wo[k * 64 + col];
        float h4 = h3s[row * 64 + col] + acc;
        h4s[row * 64 + col] = h4;
        h4g[(r0 + row) * 64 + col] = h4;        // plain store, read next kernel
    }
    __syncthreads();
    // Mt[col][r0 / r0+1] (col-major, 260 cols, 250..259 zero pad)
    if (t < 250) {
        float m0 = 0.f, m1 = 0.f;
        for (int k = 0; k < 64; ++k) {
            float w = T2[k * 250 + t];          // coalesced, feeds both rows
            m0 += h4s[k] * w;
            m1 += h4s[64 + k] * w;
        }
        Mt[(size_t)t * 1024 + r0]     = m0;
        Mt[(size_t)t * 1024 + r0 + 1] = m1;
    } else {
        Mt[(size_t)t * 1024 + r0]     = 0.f;
        Mt[(size_t)t * 1024 + r0 + 1] = 0.f;
    }
    if (t < 4) {
        Mt[(size_t)(256 + t) * 1024 + r0]     = 0.f;
        Mt[(size_t)(256 + t) * 1024 + r0 + 1] = 0.f;
    }
}

// ===========================================================================
// Kernel B: fused k3+k4. 1664 blocks (16 jt x 13 ct x 8 ic), 256 threads.
// k3 body identical to verified R6. Tail: per-jt arrival counters; the LAST
// block of each jt-tile (104 blocks) computes the 64 scores for that tile.
// No spinning anywhere -> deadlock-free. opart through agent-scope atomics.
// ===========================================================================
__global__ __launch_bounds__(256) void kB(
    const float* __restrict__ Mt, float* __restrict__ opart,
    unsigned int* __restrict__ cnt2,
    const float* __restrict__ h4g, const float* __restrict__ Ws,
    const float* __restrict__ bs, float* __restrict__ out)
{
    __shared__ float mi[2560];                  // [20 cols][128 i]
    __shared__ unsigned int lastflag;
    const int t = threadIdx.x;
    const int b = blockIdx.x;
    const int jt = b / 104;
    const int rem = b - jt * 104;
    const int ct = rem >> 3;
    const int ic = rem & 7;
    const int jl = t & 63, cl = t >> 6;
    const int j = jt * 64 + jl;
    const int c = ct * 4 + cl;                  // 0..51 (50,51 read zero pad)
    const int i0 = ic * 128;

    for (int qq = 0; qq < 10; ++qq) {
        int idx = qq * 256 + t;
        int cc = idx >> 7, il = idx & 127;
        mi[idx] = Mt[(size_t)(ct * 20 + cc) * 1024 + i0 + il];
    }
    float mj0 = Mt[(size_t)(c * 5 + 0) * 1024 + j];
    float mj1 = Mt[(size_t)(c * 5 + 1) * 1024 + j];
    float mj2 = Mt[(size_t)(c * 5 + 2) * 1024 + j];
    float mj3 = Mt[(size_t)(c * 5 + 3) * 1024 + j];
    float mj4 = Mt[(size_t)(c * 5 + 4) * 1024 + j];
    __syncthreads();

    const float2* m0 = (const float2*)(mi + (cl * 5 + 0) * 128);
    const float2* m1 = (const float2*)(mi + (cl * 5 + 1) * 128);
    const float2* m2 = (const float2*)(mi + (cl * 5 + 2) * 128);
    const float2* m3 = (const float2*)(mi + (cl * 5 + 3) * 128);
    const float2* m4 = (const float2*)(mi + (cl * 5 + 4) * 128);

    float acc0 = 0.f, acc1 = 0.f;
    for (int q = 0; q < 64; ++q) {
        float2 v0 = m0[q], v1 = m1[q], v2 = m2[q], v3 = m3[q], v4 = m4[q];
        float d0 = fabsf(v0.x - mj0) + fabsf(v1.x - mj1) + fabsf(v2.x - mj2)
                 + fabsf(v3.x - mj3) + fabsf(v4.x - mj4);
        float d1 = fabsf(v0.y - mj0) + fabsf(v1.y - mj1) + fabsf(v2.y - mj2)
                 + fabsf(v3.y - mj3) + fabsf(v4.y - mj4);
        acc0 += __expf(-d0);
        acc1 += __expf(-d1);
    }
    __hip_atomic_store(opart + (size_t)(ic * 1024 + j) * 52 + c, acc0 + acc1,
                       __ATOMIC_RELAXED, __HIP_MEMORY_SCOPE_AGENT);

    // ---- per-jt arrival; last of 104 blocks does the score tail ----
    __syncthreads();                            // drains atomic stores (vmcnt(0))
    if (t == 0) {
        __threadfence();                        // release
        lastflag = (atomicAdd(cnt2 + jt, 1u) == 103u) ? 1u : 0u;
    }
    __syncthreads();
    if (lastflag) {
        __threadfence();                        // acquire
        const int w = t >> 6, lane = t & 63;
        for (int ii = 0; ii < 16; ++ii) {
            const int jj = jt * 64 + w * 16 + ii;
            float contrib = h4g[jj * 64 + lane] * Ws[lane];
            if (lane < 50) {
                float s = 0.f;
                for (int icc = 0; icc < 8; ++icc)
                    s += __hip_atomic_load(
                        opart + (size_t)(icc * 1024 + jj) * 52 + lane,
                        __ATOMIC_RELAXED, __HIP_MEMORY_SCOPE_AGENT);
                contrib += (s - 1.0f) * Ws[64 + lane];  // -1 removes self term
            }
            for (int off = 32; off > 0; off >>= 1)
                contrib += __shfl_down(contrib, off, 64);
            if (lane == 0) out[jj] = contrib + bs[0];
        }
    }
}

// ---------------------------------------------------------------------------
// ws layout (float offsets):
//   stats @ 0      (256: sum[128], sumsq[128])
//   cnts  @ 256    (32 u32: [0]=A barrier, [1..16]=B per-jt)
//   h4    @ 512    (65536)
//   Mt    @ 66048  (260*1024 = 266240, col-major)
//   opart @ 332288 (8*1024*52 = 425984)
// total 758272 floats ~ 3.0 MB. memset zeroes first 2048 B (stats+cnts).
// ---------------------------------------------------------------------------
extern "C" void kernel_launch(void* const* d_in, const int* in_sizes, int n_in,
                              void* d_out, int out_size, void* d_ws, size_t ws_size,
                              hipStream_t stream)
{
    const float* x     = (const float*)d_in[0];
    const float* W1    = (const float*)d_in[1];
    const float* b1    = (const float*)d_in[2];
    const float* W2    = (const float*)d_in[3];
    const float* b2    = (const float*)d_in[4];
    const float* gamma = (const float*)d_in[5];
    const float* beta  = (const float*)d_in[6];
    const float* W3    = (const float*)d_in[7];
    const float* b3    = (const float*)d_in[8];
    const float* Wv    = (const float*)d_in[9];
    const float* bv    = (const float*)d_in[10];
    const float* Wo    = (const float*)d_in[11];
    const float* bo    = (const float*)d_in[12];
    const float* T2    = (const float*)d_in[13];
    const float* Ws    = (const float*)d_in[14];
    const float* bs    = (const float*)d_in[15];

    float* ws = (float*)d_ws;
    float* stats        = ws + 0;
    unsigned int* cnts  = (unsigned int*)(ws + 256);
    float* h4           = ws + 512;
    float* Mt           = ws + 66048;
    float* opart        = ws + 332288;
    float* out          = (float*)d_out;

    hipMemsetAsync(ws, 0, 2048, stream);        // stats + counters

    hipLaunchKernelGGL(kA, dim3(512), dim3(256), 0, stream,
                       x, W1, b1, W2, b2, gamma, beta, W3, b3,
                       Wv, bv, Wo, bo, T2, stats, cnts, h4, Mt);
    hipLaunchKernelGGL(kB, dim3(1664), dim3(256), 0, stream,
                       Mt, opart, cnts + 1, h4, Ws, bs, out);
}

// Round 9
// 143.278 us; speedup vs baseline: 7.7257x; 1.5581x over previous
//
#include <hip/hip_runtime.h>
#include <math.h>

#define LRELU(v) ((v) > 0.f ? (v) : 0.2f * (v))

// ===========================================================================
// Verified R6 pipeline (141.2 us, absmax 0.0), k3 inner loop upgraded:
// float4 LDS reads (ds_read_b128) + 4 independent exp/acc chains.
// NO cross-workgroup sync of any kind: CG grid.sync (R7: 330us/sync),
// spin-counter barrier (R8 kA: ~80us idle), fence+counter producer/consumer
// (R8 kB: ~60us regression) all measured FAR worse than the ~4us implicit
// kernel-boundary barrier on MI355X. Kernel boundaries stay.
// ===========================================================================

// ---------------------------------------------------------------------------
// K1: h1 = lrelu(x@W1+b1) [1024,256]; h2 = h1@W2+b2 [1024,128]; BN stats.
// 512 blocks x 256 threads, 2 rows/block.
// ---------------------------------------------------------------------------
__global__ __launch_bounds__(256) void k1_mlp12(
    const float* __restrict__ x,
    const float* __restrict__ W1, const float* __restrict__ b1,
    const float* __restrict__ W2, const float* __restrict__ b2,
    float* __restrict__ h2g, float* __restrict__ stats)
{
    __shared__ float xs[256];
    __shared__ float h1s[512];
    __shared__ float ssum[256];
    __shared__ float ssq[256];
    const int t = threadIdx.x;
    const int r0 = blockIdx.x * 2;

    xs[t] = x[r0 * 128 + t];                    // 2 rows of x, coalesced
    __syncthreads();
    {
        float a0 = b1[t], a1 = a0;
        for (int k = 0; k < 128; ++k) {
            float w = W1[k * 256 + t];          // coalesced, feeds both rows
            a0 += xs[k] * w;
            a1 += xs[128 + k] * w;
        }
        h1s[t] = LRELU(a0);
        h1s[256 + t] = LRELU(a1);
    }
    __syncthreads();
    {
        const int c = t & 127;
        const int rr = t >> 7;
        float a = b2[c];
        for (int k = 0; k < 256; ++k)
            a += h1s[rr * 256 + k] * W2[k * 128 + c];
        h2g[(r0 + rr) * 128 + c] = a;
        ssum[t] = a;                            // t == rr*128 + c
        ssq[t] = a * a;
    }
    __syncthreads();
    if (t < 128)      atomicAdd(stats + t, ssum[t] + ssum[128 + t]);
    else { int c = t - 128; atomicAdd(stats + 128 + c, ssq[c] + ssq[128 + c]); }
}

// ---------------------------------------------------------------------------
// K2: BN+lrelu -> h3 -> attn(seq=1) -> h4 -> Mt = (h4@T2)^T.
// 512 blocks x 256 threads, 2 rows/block. Mt[260][1024] col-major,
// cols 250..259 zeroed so K3's ct=12 wave reads valid zeros.
// ---------------------------------------------------------------------------
__global__ __launch_bounds__(256) void k2_bn_attn_m(
    const float* __restrict__ h2g, const float* __restrict__ stats,
    const float* __restrict__ gamma, const float* __restrict__ beta,
    const float* __restrict__ W3, const float* __restrict__ b3,
    const float* __restrict__ Wv, const float* __restrict__ bv,
    const float* __restrict__ Wo, const float* __restrict__ bo,
    const float* __restrict__ T2,
    float* __restrict__ h4g, float* __restrict__ Mt)
{
    __shared__ float a[256];
    __shared__ float h3s[128];
    __shared__ float vss[128];
    __shared__ float h4s[128];
    const int t = threadIdx.x;
    const int r0 = blockIdx.x * 2;
    {
        const int c = t & 127;
        float s = stats[c], ss = stats[128 + c];
        float mean = s * (1.f / 1024.f);
        float var = ss * (1.f / 1024.f) - mean * mean;
        float rstd = rsqrtf(var + 1e-5f);
        float v = (h2g[r0 * 128 + t] - mean) * rstd * gamma[c] + beta[c];
        a[t] = LRELU(v);
    }
    __syncthreads();
    const int row = t >> 6, col = t & 63;
    if (t < 128) {
        float acc = b3[col];
        for (int k = 0; k < 128; ++k) acc += a[row * 128 + k] * W3[k * 64 + col];
        h3s[row * 64 + col] = LRELU(acc);
    }
    __syncthreads();
    if (t < 128) {
        float acc = bv[col];
        for (int k = 0; k < 64; ++k) acc += h3s[row * 64 + k] * Wv[k * 64 + col];
        vss[row * 64 + col] = acc;
    }
    __syncthreads();
    if (t < 128) {
        float acc = bo[col];
        for (int k = 0; k < 64; ++k) acc += vss[row * 64 + k] * Wo[k * 64 + col];
        float h4 = h3s[row * 64 + col] + acc;
        h4s[row * 64 + col] = h4;
        h4g[(r0 + row) * 64 + col] = h4;
    }
    __syncthreads();
    if (t < 250) {
        float m0 = 0.f, m1 = 0.f;
        for (int k = 0; k < 64; ++k) {
            float w = T2[k * 250 + t];          // coalesced, feeds both rows
            m0 += h4s[k] * w;
            m1 += h4s[64 + k] * w;
        }
        Mt[(size_t)t * 1024 + r0]     = m0;
        Mt[(size_t)t * 1024 + r0 + 1] = m1;
    } else {
        Mt[(size_t)t * 1024 + r0]     = 0.f;
        Mt[(size_t)t * 1024 + r0 + 1] = 0.f;
    }
    if (t < 4) {
        Mt[(size_t)(256 + t) * 1024 + r0]     = 0.f;
        Mt[(size_t)(256 + t) * 1024 + r0 + 1] = 0.f;
    }
}

// ---------------------------------------------------------------------------
// K3: all-pairs L1 + exp. One (j,c) per thread.
// Grid = 16 jt x 13 ct x 8 ic = 1664 blocks (~26 waves/CU).
// LDS compute reads are wave-uniform broadcasts (cl = t>>6 const per wave);
// float4 reads -> ds_read_b128 (half the LDS instr count of float2);
// 4 independent exp/acc chains hide v_add/v_exp latency.
// ---------------------------------------------------------------------------
__global__ __launch_bounds__(256) void k3_pairs(
    const float* __restrict__ Mt, float* __restrict__ opart)
{
    __shared__ float mi[2560];                  // [20 cols][128 i]
    const int t = threadIdx.x;
    const int b = blockIdx.x;
    const int jt = b / 104;
    const int rem = b - jt * 104;
    const int ct = rem >> 3;
    const int ic = rem & 7;
    const int jl = t & 63, cl = t >> 6;
    const int j = jt * 64 + jl;
    const int c = ct * 4 + cl;                  // 0..51 (50,51 read zero pad)
    const int i0 = ic * 128;

    for (int qq = 0; qq < 10; ++qq) {
        int idx = qq * 256 + t;
        int cc = idx >> 7, il = idx & 127;
        mi[idx] = Mt[(size_t)(ct * 20 + cc) * 1024 + i0 + il];
    }
    float mj0 = Mt[(size_t)(c * 5 + 0) * 1024 + j];
    float mj1 = Mt[(size_t)(c * 5 + 1) * 1024 + j];
    float mj2 = Mt[(size_t)(c * 5 + 2) * 1024 + j];
    float mj3 = Mt[(size_t)(c * 5 + 3) * 1024 + j];
    float mj4 = Mt[(size_t)(c * 5 + 4) * 1024 + j];
    __syncthreads();

    const float4* m0 = (const float4*)(mi + (cl * 5 + 0) * 128);
    const float4* m1 = (const float4*)(mi + (cl * 5 + 1) * 128);
    const float4* m2 = (const float4*)(mi + (cl * 5 + 2) * 128);
    const float4* m3 = (const float4*)(mi + (cl * 5 + 3) * 128);
    const float4* m4 = (const float4*)(mi + (cl * 5 + 4) * 128);

    float acc0 = 0.f, acc1 = 0.f, acc2 = 0.f, acc3 = 0.f;
    for (int q = 0; q < 32; ++q) {
        float4 v0 = m0[q], v1 = m1[q], v2 = m2[q], v3 = m3[q], v4 = m4[q];
        float d0 = fabsf(v0.x - mj0) + fabsf(v1.x - mj1) + fabsf(v2.x - mj2)
                 + fabsf(v3.x - mj3) + fabsf(v4.x - mj4);
        float d1 = fabsf(v0.y - mj0) + fabsf(v1.y - mj1) + fabsf(v2.y - mj2)
                 + fabsf(v3.y - mj3) + fabsf(v4.y - mj4);
        float d2 = fabsf(v0.z - mj0) + fabsf(v1.z - mj1) + fabsf(v2.z - mj2)
                 + fabsf(v3.z - mj3) + fabsf(v4.z - mj4);
        float d3 = fabsf(v0.w - mj0) + fabsf(v1.w - mj1) + fabsf(v2.w - mj2)
                 + fabsf(v3.w - mj3) + fabsf(v4.w - mj4);
        acc0 += __expf(-d0);
        acc1 += __expf(-d1);
        acc2 += __expf(-d2);
        acc3 += __expf(-d3);
    }
    opart[(size_t)(ic * 1024 + j) * 52 + c] = (acc0 + acc1) + (acc2 + acc3);
}

// ---------------------------------------------------------------------------
// K4: reduce 8 partials, subtract self-term, dot feat=[h4,o] with Ws, +bs.
// ---------------------------------------------------------------------------
__global__ __launch_bounds__(64) void k4_score(
    const float* __restrict__ h4g, const float* __restrict__ opart,
    const float* __restrict__ Ws, const float* __restrict__ bs,
    float* __restrict__ out)
{
    const int j = blockIdx.x, t = threadIdx.x;
    float contrib = h4g[j * 64 + t] * Ws[t];
    if (t < 50) {
        float s = 0.f;
        for (int ic = 0; ic < 8; ++ic)
            s += opart[(size_t)(ic * 1024 + j) * 52 + t];
        contrib += (s - 1.0f) * Ws[64 + t];     // -1 removes self term exp(0)
    }
    for (int off = 32; off > 0; off >>= 1)
        contrib += __shfl_down(contrib, off, 64);
    if (t == 0) out[j] = contrib + bs[0];
}

// ---------------------------------------------------------------------------
// ws layout (float offsets):
//   h2    @ 0       (131072)
//   stats @ 131072  (256)
//   h4    @ 131328  (65536)
//   Mt    @ 196864  (260*1024 = 266240, col-major transpose of M)
//   opart @ 463104  (8*1024*52 = 425984)
// ---------------------------------------------------------------------------
extern "C" void kernel_launch(void* const* d_in, const int* in_sizes, int n_in,
                              void* d_out, int out_size, void* d_ws, size_t ws_size,
                              hipStream_t stream)
{
    const float* x     = (const float*)d_in[0];
    const float* W1    = (const float*)d_in[1];
    const float* b1    = (const float*)d_in[2];
    const float* W2    = (const float*)d_in[3];
    const float* b2    = (const float*)d_in[4];
    const float* gamma = (const float*)d_in[5];
    const float* beta  = (const float*)d_in[6];
    const float* W3    = (const float*)d_in[7];
    const float* b3    = (const float*)d_in[8];
    const float* Wv    = (const float*)d_in[9];
    const float* bv    = (const float*)d_in[10];
    const float* Wo    = (const float*)d_in[11];
    const float* bo    = (const float*)d_in[12];
    const float* T2    = (const float*)d_in[13];
    const float* Ws    = (const float*)d_in[14];
    const float* bs    = (const float*)d_in[15];

    float* ws    = (float*)d_ws;
    float* h2    = ws + 0;
    float* stats = ws + 131072;
    float* h4    = ws + 131328;
    float* Mt    = ws + 196864;
    float* opart = ws + 463104;
    float* out   = (float*)d_out;

    hipMemsetAsync(stats, 0, 256 * sizeof(float), stream);
    hipLaunchKernelGGL(k1_mlp12, dim3(512), dim3(256), 0, stream,
                       x, W1, b1, W2, b2, h2, stats);
    hipLaunchKernelGGL(k2_bn_attn_m, dim3(512), dim3(256), 0, stream,
                       h2, stats, gamma, beta, W3, b3, Wv, bv, Wo, bo, T2, h4, Mt);
    hipLaunchKernelGGL(k3_pairs, dim3(1664), dim3(256), 0, stream, Mt, opart);
    hipLaunchKernelGGL(k4_score, dim3(1024), dim3(64), 0, stream,
                       h4, opart, Ws, bs, out);
}